// Round 1
// baseline (47.078 us; speedup 1.0000x reference)
//
#include <hip/hip_runtime.h>
#include <math.h>

#define NPART 8
#define NN    128   // neighbors per batch
#define TT    8     // timesteps

// One block per batch element b. threadIdx.x = neighbor index n (0..127).
// Phase 1: each thread reads its neighbor's 16 floats (4x float4), computes
//          velocity/distance/direction + validity, LDS-atomic accumulates
//          into 8 angle bins (3 sums + count each).
// Phase 2: 24 threads finalize social_circle = sum/(cnt+eps), write output 1.
// Phase 3: thread c computes f_sc[b,p,c] = relu(sc[p,:] . W[:,c] + b[c]) for
//          all 8 partitions (coalesced stores).
__global__ __launch_bounds__(128) void sc_kernel(
    const float* __restrict__ nei,   // (B, 128, 8, 2) f32
    const float* __restrict__ W,     // (3, 128) f32
    const float* __restrict__ bce,   // (128,) f32
    float* __restrict__ fsc,         // (B, 8, 128) f32
    float* __restrict__ scout,       // (B, 8, 3) f32
    int Btot)
{
    const int b = blockIdx.x;
    if (b >= Btot) return;
    const int tid = threadIdx.x;

    __shared__ float s_sum[NPART * 3];
    __shared__ float s_cnt[NPART];
    __shared__ float s_sc[NPART * 3];

    if (tid < NPART * 3) s_sum[tid] = 0.0f;
    if (tid < NPART)     s_cnt[tid] = 0.0f;
    __syncthreads();

    // ---- Phase 1: per-neighbor features ----
    const float4* p4 = reinterpret_cast<const float4*>(nei) + ((size_t)b * NN + tid) * 4;
    float4 a = p4[0];   // t0x t0y t1x t1y
    float4 c = p4[1];   // t2x t2y t3x t3y
    float4 d = p4[2];   // t4x t4y t5x t5y
    float4 e = p4[3];   // t6x t6y t7x t7y

    // full-sum mask (reference: sum over all T,2 != 0)
    float total = (((a.x + a.y) + (a.z + a.w)) + ((c.x + c.y) + (c.z + c.w)))
                + (((d.x + d.y) + (d.z + d.w)) + ((e.x + e.y) + (e.z + e.w)));

    float px = e.z, py = e.w;          // last position (t7)
    float vx = px - a.x, vy = py - a.y; // last - first
    float fvel  = sqrtf(vx * vx + vy * vy);
    float fdist = sqrtf(px * px + py * py);

    // f_direction = atan2(x, y) mod 2pi   (floor-mod into [0, 2pi))
    float fdir = atan2f(px, py);
    if (fdir < 0.0f) fdir += 6.2831853071795864769f;

    // angle_idx = trunc(f_direction / (2pi/8)); idx==8 edge or masked -> excluded
    const float STEP = (float)(6.283185307179586 / 8.0);
    int idx = (int)(fdir / STEP);

    if (total != 0.0f && idx >= 0 && idx < NPART) {
        atomicAdd(&s_sum[idx * 3 + 0], fvel);
        atomicAdd(&s_sum[idx * 3 + 1], fdist);
        atomicAdd(&s_sum[idx * 3 + 2], fdir);
        atomicAdd(&s_cnt[idx], 1.0f);
    }
    __syncthreads();

    // ---- Phase 2: social_circle finalize + write output 1 ----
    if (tid < NPART * 3) {
        float v = s_sum[tid] / (s_cnt[tid / 3] + 0.0001f);
        s_sc[tid] = v;
        scout[(size_t)b * (NPART * 3) + tid] = v;
    }
    __syncthreads();

    // ---- Phase 3: f_sc = relu(sc @ W + b), thread = output column ----
    float w0 = W[tid], w1 = W[NN + tid], w2 = W[2 * NN + tid];
    float bb = bce[tid];
    float* o = fsc + (size_t)b * NPART * NN;
    #pragma unroll
    for (int p = 0; p < NPART; ++p) {
        float acc = bb;
        acc = fmaf(s_sc[p * 3 + 0], w0, acc);
        acc = fmaf(s_sc[p * 3 + 1], w1, acc);
        acc = fmaf(s_sc[p * 3 + 2], w2, acc);
        o[p * NN + tid] = fmaxf(acc, 0.0f);
    }
}

extern "C" void kernel_launch(void* const* d_in, const int* in_sizes, int n_in,
                              void* d_out, int out_size, void* d_ws, size_t ws_size,
                              hipStream_t stream) {
    // inputs: 0=trajs (UNUSED by reference), 1=nei_trajs, 2=W_ce, 3=b_ce
    const float* nei = (const float*)d_in[1];
    const float* W   = (const float*)d_in[2];
    const float* bce = (const float*)d_in[3];

    const int Btot = in_sizes[1] / (NN * TT * 2);   // 16384

    // outputs concatenated: f_sc (B,8,128) then social_circle (B,8,3)
    float* fsc   = (float*)d_out;
    float* scout = fsc + (size_t)Btot * NPART * NN;

    sc_kernel<<<Btot, 128, 0, stream>>>(nei, W, bce, fsc, scout, Btot);
}